// Round 5
// baseline (4549.752 us; speedup 1.0000x reference)
//
#include <hip/hip_runtime.h>
#include <math.h>

// Problem constants
#define Bb 64
#define Tt 1024
#define Dd 512
#define Hh 512

// ---------------------------------------------------------------------------
// Kernel 1: xw = x @ W[:D] + b   (M=65536, K=512, N=512), fp32.
// Unchanged (~470 us). Writes into d_out; scan overwrites in place.
// ---------------------------------------------------------------------------
#define TM 128
#define TN 128
#define TK 16
#define LDP (TN + 4)

__global__ __launch_bounds__(256) void gemm_xw(const float* __restrict__ x,
                                               const float* __restrict__ W,
                                               const float* __restrict__ bias,
                                               float* __restrict__ out) {
    __shared__ float As[TK][LDP];
    __shared__ float Bs[TK][LDP];

    const int tid = threadIdx.x;
    const int m0 = blockIdx.x * TM;
    const int n0 = blockIdx.y * TN;
    const int tx = tid & 15;
    const int ty = tid >> 4;

    float acc[8][8];
    #pragma unroll
    for (int i = 0; i < 8; i++)
        #pragma unroll
        for (int j = 0; j < 8; j++) acc[i][j] = 0.0f;

    for (int k0 = 0; k0 < Dd; k0 += TK) {
        #pragma unroll
        for (int i = 0; i < 2; i++) {
            const int idx = tid * 2 + i;
            const int r = idx >> 2;
            const int c = idx & 3;
            const float4 av = *(const float4*)(x + (size_t)(m0 + r) * Dd + k0 + c * 4);
            As[c * 4 + 0][r] = av.x;
            As[c * 4 + 1][r] = av.y;
            As[c * 4 + 2][r] = av.z;
            As[c * 4 + 3][r] = av.w;
            const int kk = idx >> 5;
            const int cg = (idx & 31) * 4;
            const float4 bv = *(const float4*)(W + (size_t)(k0 + kk) * Hh + n0 + cg);
            *(float4*)(&Bs[kk][cg]) = bv;
        }
        __syncthreads();

        #pragma unroll
        for (int kk = 0; kk < TK; kk++) {
            float a[8], b[8];
            #pragma unroll
            for (int i = 0; i < 8; i++) a[i] = As[kk][ty * 8 + i];
            #pragma unroll
            for (int j = 0; j < 8; j++) b[j] = Bs[kk][tx * 8 + j];
            #pragma unroll
            for (int i = 0; i < 8; i++)
                #pragma unroll
                for (int j = 0; j < 8; j++) acc[i][j] += a[i] * b[j];
        }
        __syncthreads();
    }

    #pragma unroll
    for (int i = 0; i < 8; i++) {
        const size_t row = (size_t)(m0 + ty * 8 + i) * Hh;
        const int n = n0 + tx * 8;
        float4 v0, v1;
        v0.x = acc[i][0] + bias[n + 0];
        v0.y = acc[i][1] + bias[n + 1];
        v0.z = acc[i][2] + bias[n + 2];
        v0.w = acc[i][3] + bias[n + 3];
        v1.x = acc[i][4] + bias[n + 4];
        v1.y = acc[i][5] + bias[n + 5];
        v1.z = acc[i][6] + bias[n + 6];
        v1.w = acc[i][7] + bias[n + 7];
        *(float4*)(out + row + n) = v0;
        *(float4*)(out + row + n + 4) = v1;
    }
}

// ---------------------------------------------------------------------------
// Kernel 2: scan with DUAL-PATH exchange: same-XCD L2 fast lane + IC fallback.
//
// R5 post-mortem: three schedules (2-bar LDS-h / 1-bar reg-h / 2-row
// pipelined) all pin at ~1.9-2.0 us/step -> the agent-atomic exchange
// (publish -> IC-visible -> poll-detect, ~2200-2700 cy) IS the step period.
// Agent atomics execute at the Infinity Cache because per-XCD L2s aren't
// cross-coherent. But a row's 4 partner blocks land on ONE XCD under
// round-robin dispatch (bids {r,64+r,128+r,192+r} all = r mod 8), where a
// plain write-through store + sc0 (L1-bypass, L2-hit) load is coherent
// through the shared L2 at ~400 cy round trip — 5x faster.
//
// Placement safety (Guideline 16 — correctness must NOT depend on XCD
// assignment):
//   - Producers DUAL-PUBLISH each tagged u64: workgroup-scope plain store
//     to g_fast (lands in local L2) AND agent-scope store to g_hbuf (IC
//     mirror, the proven R3 path).
//   - Pollers try the fast buffer first; after 4096 failed spins they
//     permanently (per-launch, register-sticky) switch to the agent
//     mirror, which has the dead-man (2^16 spins -> sdead free-run).
//     Mode resets each launch -> placement changes across replays
//     self-correct. Worst case = R3 speed + one-time ~0.5 ms probe.
//   - Stale-tag audit (both buffers, .bss zero-init): a slot's first two
//     in-replay wants are 1 and 2 vs possible stale tags 1022/1023 from a
//     prior replay -> no false positive before hundreds of fresh
//     overwrites; later wants only see fresh tags. Tag+data share one
//     aligned u64 (no tearing).
//
// Protocol per row otherwise unchanged (self-tagged u64, parity slots,
// skew <= 1 step induction). Weights fp32 register-resident (keep-alive);
// 256 blocks = 1/CU, capacity-exact.
// ---------------------------------------------------------------------------
__device__ unsigned long long g_hbuf[(size_t)Bb * 2 * Hh];   // IC mirror
__device__ unsigned long long g_fast[(size_t)Bb * 2 * Hh];   // same-XCD L2 lane

__global__ __launch_bounds__(1024, 4) void scan_rnn(const float* __restrict__ W,
                                                    float* __restrict__ out) {
    const float* __restrict__ Wh = W + (size_t)Dd * Hh;   // (H, H) row-major
    const int r = blockIdx.x & 63;        // batch row
    const int c = blockIdx.x >> 6;        // column group, 0..3 (cols 128c..)
    const int tid = threadIdx.x;
    const int g = tid & 31;               // 4-col group within slice
    const int s = tid >> 5;               // k-slice, 0..31

    float* rowbase = out + (size_t)r * Tt * Hh;
    unsigned long long* hrow = g_hbuf + (size_t)r * 2 * Hh;  // [2][512] u64
    unsigned long long* frow = g_fast + (size_t)r * 2 * Hh;

    __shared__ float hs[Hh];              // full h_{t-1}
    __shared__ float ps[32][128];         // partials [s][j_local]
    __shared__ int sdead;                 // dead-man flag

    // ---- weight slice in registers: w4[kk] = Wh[16s+kk][128c+4g .. +3]
    float4 w4[16];
    {
        const float4* wbase = (const float4*)(Wh + (size_t)(s * 16) * Hh) + (c * 32 + g);
        #pragma unroll
        for (int kk = 0; kk < 16; kk++) w4[kk] = wbase[(size_t)kk * 128];
    }
    #pragma unroll
    for (int kk = 0; kk < 16; kk++)
        asm volatile("" : "+v"(w4[kk].x), "+v"(w4[kk].y), "+v"(w4[kk].z), "+v"(w4[kk].w));

    if (tid < Hh) hs[tid] = 0.0f;
    if (tid == 0) sdead = 0;
    __syncthreads();

    bool fastmode = true;                 // per-launch sticky (poll threads)

    for (int t = 0; t < Tt; t++) {
        // A: prefetch xw for own columns (L2-warm from gemm_xw)
        float z = 0.0f;
        if (tid < 128) z = rowbase[(size_t)t * Hh + c * 128 + tid];

        // B: FMA phase — 64 MACs/thread, register weights + LDS h_{t-1}
        float4 acc; acc.x = acc.y = acc.z = acc.w = 0.0f;
        #pragma unroll
        for (int kq = 0; kq < 4; kq++) {
            const float4 hv = *(const float4*)&hs[s * 16 + kq * 4];
            const float4 a0 = w4[kq * 4 + 0];
            const float4 a1 = w4[kq * 4 + 1];
            const float4 a2 = w4[kq * 4 + 2];
            const float4 a3 = w4[kq * 4 + 3];
            acc.x += hv.x * a0.x; acc.y += hv.x * a0.y; acc.z += hv.x * a0.z; acc.w += hv.x * a0.w;
            acc.x += hv.y * a1.x; acc.y += hv.y * a1.y; acc.z += hv.y * a1.z; acc.w += hv.y * a1.w;
            acc.x += hv.z * a2.x; acc.y += hv.z * a2.y; acc.z += hv.z * a2.z; acc.w += hv.z * a2.w;
            acc.x += hv.w * a3.x; acc.y += hv.w * a3.y; acc.z += hv.w * a3.z; acc.w += hv.w * a3.w;
        }
        *(float4*)&ps[s][g * 4] = acc;
        __syncthreads();            // ps ready; all hs reads of h_{t-1} done
        const int dead = sdead;

        if (tid < 128) {
            // C: reduce + tanh + DUAL publish (fast lane first — critical path)
            #pragma unroll
            for (int q = 0; q < 32; q++) z += ps[q][tid];
            const float hn = tanhf(z);
            if (t < Tt - 1) {
                const size_t idx = (size_t)(t & 1) * Hh + c * 128 + tid;
                const unsigned long long pkt =
                    ((unsigned long long)(unsigned)(t + 1) << 32) | __float_as_uint(hn);
                __hip_atomic_store(&frow[idx], pkt, __ATOMIC_RELAXED,
                                   __HIP_MEMORY_SCOPE_WORKGROUP);   // plain store -> local L2
                __hip_atomic_store(&hrow[idx], pkt, __ATOMIC_RELAXED,
                                   __HIP_MEMORY_SCOPE_AGENT);       // IC mirror
                hs[c * 128 + tid] = hn;
            }
            rowbase[(size_t)t * Hh + c * 128 + tid] = hn;   // output (write-only)
        } else if (tid < 512 && t < Tt - 1) {
            // D: pull partners' h_t — fast L2 lane, sticky fallback to IC
            const int p_ = (tid >> 7) - 1;           // 0..2
            const int cp = p_ + (p_ >= c ? 1 : 0);
            const int jj = tid & 127;
            const size_t idx = (size_t)(t & 1) * Hh + cp * 128 + jj;
            const unsigned want = (unsigned)(t + 1);
            unsigned long long v = 0;
            bool got = false;
            if (!dead && fastmode) {
                const unsigned long long* srcF = frow + idx;
                int spins = 0;
                for (;;) {
                    // L1-bypass, L2-served load (same-XCD coherent lane)
                    asm volatile("global_load_dwordx2 %0, %1, off sc0\n\t"
                                 "s_waitcnt vmcnt(0)"
                                 : "=&v"(v) : "v"(srcF) : "memory");
                    if ((unsigned)(v >> 32) == want) { got = true; break; }
                    if (++spins > 4096) { fastmode = false; break; }  // placement broken
                }
            }
            if (!dead && !got) {
                int spins = 0;
                for (;;) {
                    v = __hip_atomic_load(&hrow[idx], __ATOMIC_RELAXED,
                                          __HIP_MEMORY_SCOPE_AGENT);
                    if ((unsigned)(v >> 32) == want) break;
                    if (++spins > 64) __builtin_amdgcn_s_sleep(1);
                    if (spins > (1 << 16)) { sdead = 1; break; }      // dead-man
                }
            }
            hs[cp * 128 + jj] = __uint_as_float((unsigned)v);
        }
        __syncthreads();            // hs = full h_t
    }
}

// ---------------------------------------------------------------------------
extern "C" void kernel_launch(void* const* d_in, const int* in_sizes, int n_in,
                              void* d_out, int out_size, void* d_ws, size_t ws_size,
                              hipStream_t stream) {
    const float* x = (const float*)d_in[0];    // (B, T, D)
    const float* W = (const float*)d_in[1];    // (D+H, H)
    const float* b = (const float*)d_in[2];    // (H,)
    float* out = (float*)d_out;                // (B, T, H)
    (void)d_ws; (void)ws_size;

    dim3 ggrid((Bb * Tt) / TM, Hh / TN);       // 512 x 4
    gemm_xw<<<ggrid, dim3(256), 0, stream>>>(x, W, b, out);
    scan_rnn<<<dim3(256), dim3(1024), 0, stream>>>(W, out);
}

// Round 6
// 2234.530 us; speedup vs baseline: 2.0361x; 2.0361x over previous
//
#include <hip/hip_runtime.h>
#include <math.h>

// Problem constants
#define Bb 64
#define Tt 1024
#define Dd 512
#define Hh 512

// ---------------------------------------------------------------------------
// Kernel 1: xw = x @ W[:D] + b   (M=65536, K=512, N=512), fp32.
// Unchanged (~470 us). Writes into d_out; scan overwrites in place.
// ---------------------------------------------------------------------------
#define TM 128
#define TN 128
#define TK 16
#define LDP (TN + 4)

__global__ __launch_bounds__(256) void gemm_xw(const float* __restrict__ x,
                                               const float* __restrict__ W,
                                               const float* __restrict__ bias,
                                               float* __restrict__ out) {
    __shared__ float As[TK][LDP];
    __shared__ float Bs[TK][LDP];

    const int tid = threadIdx.x;
    const int m0 = blockIdx.x * TM;
    const int n0 = blockIdx.y * TN;
    const int tx = tid & 15;
    const int ty = tid >> 4;

    float acc[8][8];
    #pragma unroll
    for (int i = 0; i < 8; i++)
        #pragma unroll
        for (int j = 0; j < 8; j++) acc[i][j] = 0.0f;

    for (int k0 = 0; k0 < Dd; k0 += TK) {
        #pragma unroll
        for (int i = 0; i < 2; i++) {
            const int idx = tid * 2 + i;
            const int r = idx >> 2;
            const int c = idx & 3;
            const float4 av = *(const float4*)(x + (size_t)(m0 + r) * Dd + k0 + c * 4);
            As[c * 4 + 0][r] = av.x;
            As[c * 4 + 1][r] = av.y;
            As[c * 4 + 2][r] = av.z;
            As[c * 4 + 3][r] = av.w;
            const int kk = idx >> 5;
            const int cg = (idx & 31) * 4;
            const float4 bv = *(const float4*)(W + (size_t)(k0 + kk) * Hh + n0 + cg);
            *(float4*)(&Bs[kk][cg]) = bv;
        }
        __syncthreads();

        #pragma unroll
        for (int kk = 0; kk < TK; kk++) {
            float a[8], b[8];
            #pragma unroll
            for (int i = 0; i < 8; i++) a[i] = As[kk][ty * 8 + i];
            #pragma unroll
            for (int j = 0; j < 8; j++) b[j] = Bs[kk][tx * 8 + j];
            #pragma unroll
            for (int i = 0; i < 8; i++)
                #pragma unroll
                for (int j = 0; j < 8; j++) acc[i][j] += a[i] * b[j];
        }
        __syncthreads();
    }

    #pragma unroll
    for (int i = 0; i < 8; i++) {
        const size_t row = (size_t)(m0 + ty * 8 + i) * Hh;
        const int n = n0 + tx * 8;
        float4 v0, v1;
        v0.x = acc[i][0] + bias[n + 0];
        v0.y = acc[i][1] + bias[n + 1];
        v0.z = acc[i][2] + bias[n + 2];
        v0.w = acc[i][3] + bias[n + 3];
        v1.x = acc[i][4] + bias[n + 4];
        v1.y = acc[i][5] + bias[n + 5];
        v1.z = acc[i][6] + bias[n + 6];
        v1.w = acc[i][7] + bias[n + 7];
        *(float4*)(out + row + n) = v0;
        *(float4*)(out + row + n + 4) = v1;
    }
}

// ---------------------------------------------------------------------------
// Kernel 2: scan — exact R3 protocol (proven 1950 us), ONE change:
// the poll loop's s_sleep(1) is replaced by a ~64-cycle dependent-ALU
// filler (hot spin, no sleep).
//
// R6 post-mortem: dual-path L2 fast lane REVERTED. CDNA L2 is write-back,
// so the plain-store publish sat dirty in the producer's L2; consumers'
// sc0 probes failed except when natural eviction leaked the line to IC —
// intermittent success kept the sticky fastmode alive, so pollers burned
// up to 4096 probes EVERY step (1936 -> 4220 us, VALUBusy 8.9%).
//
// Current theory for the remaining wall: three schedules (R3/R4/R5) all
// pin at ~1.9 us/step. Wall-clock-derived exchange latency (~3300 cy @
// 2.4 GHz) is 2-3x the first-principles chain (store->IC + IC load return
// ~ 1000-1500 cy). With VALUBusy 17%, waves parked at barriers, and
// pollers in s_sleep, the DPM governor plausibly drops SCLK — inflating
// every microsecond. Test: keep the polling waves ISSUING (dependent ALU
// chain between probes) instead of sleeping. Same memory traffic shape
// (one agent probe per ~800 cy); only the activity profile changes.
//   - droop true  -> scan ~1300-1550 us, VALUBusy ~30%+
//   - droop false -> neutral (~1900-2100), pivot to gemm-scan fusion.
//
// Protocol unchanged from R3 (self-tagged u64 RELAXED agent atomics,
// parity-2 slots, skew<=1 induction, cross-replay-safe exact-match tags,
// dead-man -> sdead free-run). Weights fp32 register/AGPR-resident via
// keep-alive; 256 blocks = 1/CU capacity-exact.
// ---------------------------------------------------------------------------
__device__ unsigned long long g_hbuf[(size_t)Bb * 2 * Hh];   // 512 KB .bss

__global__ __launch_bounds__(1024, 4) void scan_rnn(const float* __restrict__ W,
                                                    float* __restrict__ out) {
    const float* __restrict__ Wh = W + (size_t)Dd * Hh;   // (H, H) row-major
    const int r = blockIdx.x & 63;        // batch row
    const int c = blockIdx.x >> 6;        // column group, 0..3 (cols 128c..)
    const int tid = threadIdx.x;
    const int g = tid & 31;               // 4-col group within slice
    const int s = tid >> 5;               // k-slice, 0..31

    float* rowbase = out + (size_t)r * Tt * Hh;
    unsigned long long* hrow = g_hbuf + (size_t)r * 2 * Hh;  // [2][512] u64

    __shared__ float hs[Hh];              // full h_{t-1}
    __shared__ float ps[32][128];         // partials [s][j_local]
    __shared__ int sdead;                 // dead-man flag

    // ---- weight slice in registers: w4[kk] = Wh[16s+kk][128c+4g .. +3]
    float4 w4[16];
    {
        const float4* wbase = (const float4*)(Wh + (size_t)(s * 16) * Hh) + (c * 32 + g);
        #pragma unroll
        for (int kk = 0; kk < 16; kk++) w4[kk] = wbase[(size_t)kk * 128];
    }
    #pragma unroll
    for (int kk = 0; kk < 16; kk++)
        asm volatile("" : "+v"(w4[kk].x), "+v"(w4[kk].y), "+v"(w4[kk].z), "+v"(w4[kk].w));

    if (tid < Hh) hs[tid] = 0.0f;
    if (tid == 0) sdead = 0;
    __syncthreads();

    unsigned fil = tid * 2654435761u;     // ALU-filler state (poll threads)

    for (int t = 0; t < Tt; t++) {
        // A: prefetch xw for own columns
        float z = 0.0f;
        if (tid < 128) z = rowbase[(size_t)t * Hh + c * 128 + tid];

        // B: FMA phase — 64 MACs/thread, register weights + LDS h_{t-1}
        float4 acc; acc.x = acc.y = acc.z = acc.w = 0.0f;
        #pragma unroll
        for (int kq = 0; kq < 4; kq++) {
            const float4 hv = *(const float4*)&hs[s * 16 + kq * 4];
            const float4 a0 = w4[kq * 4 + 0];
            const float4 a1 = w4[kq * 4 + 1];
            const float4 a2 = w4[kq * 4 + 2];
            const float4 a3 = w4[kq * 4 + 3];
            acc.x += hv.x * a0.x; acc.y += hv.x * a0.y; acc.z += hv.x * a0.z; acc.w += hv.x * a0.w;
            acc.x += hv.y * a1.x; acc.y += hv.y * a1.y; acc.z += hv.y * a1.z; acc.w += hv.y * a1.w;
            acc.x += hv.z * a2.x; acc.y += hv.z * a2.y; acc.z += hv.z * a2.z; acc.w += hv.z * a2.w;
            acc.x += hv.w * a3.x; acc.y += hv.w * a3.y; acc.z += hv.w * a3.z; acc.w += hv.w * a3.w;
        }
        *(float4*)&ps[s][g * 4] = acc;
        __syncthreads();            // ps ready; all hs reads of h_{t-1} done
        const int dead = sdead;

        if (tid < 128) {
            // C: reduce + tanh + publish (publish first — critical path)
            #pragma unroll
            for (int q = 0; q < 32; q++) z += ps[q][tid];
            const float hn = tanhf(z);
            if (t < Tt - 1) {
                const unsigned long long pkt =
                    ((unsigned long long)(unsigned)(t + 1) << 32) | __float_as_uint(hn);
                __hip_atomic_store(&hrow[(size_t)(t & 1) * Hh + c * 128 + tid], pkt,
                                   __ATOMIC_RELAXED, __HIP_MEMORY_SCOPE_AGENT);
                hs[c * 128 + tid] = hn;
            }
            rowbase[(size_t)t * Hh + c * 128 + tid] = hn;   // output (write-only)
        } else if (tid < 512 && t < Tt - 1) {
            // D: pull partners' h_t — hot spin with ALU filler (NO s_sleep)
            const int p_ = (tid >> 7) - 1;           // 0..2
            const int cp = p_ + (p_ >= c ? 1 : 0);
            const int jj = tid & 127;
            unsigned long long* src = &hrow[(size_t)(t & 1) * Hh + cp * 128 + jj];
            const unsigned want = (unsigned)(t + 1);
            unsigned long long v = 0;
            if (!dead) {
                int spins = 0;
                for (;;) {
                    v = __hip_atomic_load(src, __ATOMIC_RELAXED,
                                          __HIP_MEMORY_SCOPE_AGENT);
                    if ((unsigned)(v >> 32) == want) break;
                    // ~64-cycle dependent ALU chain: keeps the SIMD issuing
                    // (clock-governor activity) without extra memory traffic.
                    #pragma unroll
                    for (int u = 0; u < 16; u++)
                        fil = (fil << 1) ^ (fil + 0x9E3779B9u);
                    asm volatile("" : "+v"(fil));    // keep chain live
                    if (++spins > (1 << 16)) { sdead = 1; break; }   // dead-man
                }
            }
            hs[cp * 128 + jj] = __uint_as_float((unsigned)v);
        }
        __syncthreads();            // hs = full h_t
    }
}

// ---------------------------------------------------------------------------
extern "C" void kernel_launch(void* const* d_in, const int* in_sizes, int n_in,
                              void* d_out, int out_size, void* d_ws, size_t ws_size,
                              hipStream_t stream) {
    const float* x = (const float*)d_in[0];    // (B, T, D)
    const float* W = (const float*)d_in[1];    // (D+H, H)
    const float* b = (const float*)d_in[2];    // (H,)
    float* out = (float*)d_out;                // (B, T, H)
    (void)d_ws; (void)ws_size;

    dim3 ggrid((Bb * Tt) / TM, Hh / TN);       // 512 x 4
    gemm_xw<<<ggrid, dim3(256), 0, stream>>>(x, W, b, out);
    scan_rnn<<<dim3(256), dim3(1024), 0, stream>>>(W, out);
}